// Round 7
// baseline (137.327 us; speedup 1.0000x reference)
//
#include <hip/hip_runtime.h>
#include <math.h>

#define NUM_E   100000
#define GAMMA_F 12.0f
#define EMB_RANGE_F 0.21875f                       // (12+2)/64
#define INV_TWO_EMB (1.0f / (2.0f * EMB_RANGE_F))  // rev = r * this = phase/(2pi)

typedef float v4f __attribute__((ext_vector_type(4)));
typedef float v2f __attribute__((ext_vector_type(2)));

// ---- packed-f32 VALU (VOP3P): 2 dims per instruction ----
static __device__ __forceinline__ v2f pk_sub(v2f a, v2f b) {
    v2f d;
    asm("v_pk_add_f32 %0, %1, %2 neg_lo:[0,1] neg_hi:[0,1]"
        : "=v"(d) : "v"(a), "v"(b));
    return d;
}
static __device__ __forceinline__ v2f pk_mul(v2f a, v2f b) {
    v2f d;
    asm("v_pk_mul_f32 %0, %1, %2" : "=v"(d) : "v"(a), "v"(b));
    return d;
}
static __device__ __forceinline__ v2f pk_fma(v2f a, v2f b, v2f c) {
    v2f d;
    asm("v_pk_fma_f32 %0, %1, %2, %3" : "=v"(d) : "v"(a), "v"(b), "v"(c));
    return d;
}
static __device__ __forceinline__ float sq2(v2f dx, v2f dy) {
    v2f sq = pk_fma(dy, dy, pk_mul(dx, dx));
    return __builtin_amdgcn_sqrtf(sq.x) + __builtin_amdgcn_sqrtf(sq.y);
}
static __device__ __forceinline__ v2f lo2(v4f v) { return __builtin_shufflevector(v, v, 0, 1); }
static __device__ __forceinline__ v2f hi2(v4f v) { return __builtin_shufflevector(v, v, 2, 3); }

// cross-lane add via DPP (VALU pipe, no DS, no lgkm wait)
// 0xB1 = quad_perm [1,0,3,2] (xor1), 0x4E = quad_perm [2,3,0,1] (xor2),
// 0x141 = row_half_mirror: after xor1+xor2, mirrors within each aligned 8-lane
// half -> adds the other quad. Valid for any aligned 8-lane reduce group.
template <int CTRL>
static __device__ __forceinline__ float dpp_xor_add(float x) {
    int y = __builtin_amdgcn_update_dpp(0, __float_as_int(x), CTRL, 0xF, 0xF, true);
    return x + __int_as_float(y);
}

// distance for ONE entity against this lane's 1 batch x 8 dims, reduced over
// the 8 dg lanes of the batch-group (all 8 lanes end up with the result)
static __device__ __forceinline__ float dist_entity(
        v4f er0, v4f er1, v4f ei0, v4f ei1,
        const v2f RR[4], const v2f RI[4]) {
    v2f e2[4] = { lo2(er0), hi2(er0), lo2(er1), hi2(er1) };
    v2f i2[4] = { lo2(ei0), hi2(ei0), lo2(ei1), hi2(ei1) };
    float s0 = sq2(pk_sub(RR[0], e2[0]), pk_sub(RI[0], i2[0]));
    float s1 = sq2(pk_sub(RR[1], e2[1]), pk_sub(RI[1], i2[1]));
    float s2 = sq2(pk_sub(RR[2], e2[2]), pk_sub(RI[2], i2[2]));
    float s3 = sq2(pk_sub(RR[3], e2[3]), pk_sub(RI[3], i2[3]));
    float v = (s0 + s1) + (s2 + s3);
    v = dpp_xor_add<0xB1>(v);            // xor1 (within quad)
    v = dpp_xor_add<0x4E>(v);            // xor2 (within quad)
    v = dpp_xor_add<0x141>(v);           // xor4 via row_half_mirror
    return GAMMA_F - v;
}

#define LOADE(d0, d1, d2, d3, EIDX) do {                         \
    const float* _p = ent + (size_t)(EIDX) * 128 + dg * 8;       \
    d0 = *(const v4f*)(_p);      d1 = *(const v4f*)(_p + 4);     \
    d2 = *(const v4f*)(_p + 64); d3 = *(const v4f*)(_p + 68); } while (0)

// R13: batch-split decomposition -- make the allocator's preferred envelope
// (<=64 VGPR, 8 waves/SIMD) the natural one instead of fighting it.
// R11/R12 evidence: a lane holding the full 32-batch rot table (64 f32) can
// never be register-resident at the compiler's chosen 60-reg allocation; it
// remats from LDS at ~16 ds_read_b128/entity = ~31us of per-CU LDS pipe = the
// entire gap to the issue floor. R12's empty-asm pin was duplicated into the
// loop (non-volatile asm is clonable) and changed nothing.
// New shape:
//  - Block = 4 waves x 16 entities. Wave wv owns batches wv*8..wv*8+7.
//  - lane=(bq,dg): batch wv*8+bq, dims dg*8..dg*8+7. Per-lane rot = 16 f32.
//  - Each wave computes its rot slice with v_sin/v_cos in ~150cy (amortized
//    over 16 entities). NO LDS, NO __syncthreads in the kernel at all.
//  - Entity rows read by 4 waves each (broadcast dedup within wave; L2/L3
//    absorb cross-wave reuse -- we run at 10% HBM, traffic is free).
//  - A/B register double-buffer prefetch down the 16-entity stream.
//  - Store: after the 8-lane DPP reduce every lane holds the batch result;
//    quad q is stored by lanes with dg==q as one dwordx4 per batch row.
__global__ __launch_bounds__(256, 2) void rotate_dist_fused(
        const int*   __restrict__ facts,
        const float* __restrict__ ent,
        const float* __restrict__ rel,
        float*       __restrict__ out) {
    const int t    = threadIdx.x;
    const int lane = t & 63;
    const int wv   = t >> 6;
    const int bq   = lane >> 3;         // batch-in-wave 0..7
    const int dg   = lane & 7;          // dims 8dg..8dg+7
    const int b    = wv * 8 + bq;       // global batch 0..31
    const int e0   = blockIdx.x * 16;   // this block's 16 entities

    // issue first entity load immediately; prologue compute hides its latency
    v4f A0, A1, A2, A3, B0, B1, B2, B3;
    LOADE(A0, A1, A2, A3, e0);

    // ---- prologue: this lane's rot slice (1 batch x 8 dims) in registers ----
    v2f RR[4], RI[4];
    {
        const int f0 = facts[b * 3 + 0];
        const int f1 = facts[b * 3 + 1];
        const float* hp = ent + (size_t)f0 * 128 + dg * 8;
        const float* rp = rel + (size_t)f1 * 64  + dg * 8;
        v4f hre0 = *(const v4f*)(hp);
        v4f hre1 = *(const v4f*)(hp + 4);
        v4f him0 = *(const v4f*)(hp + 64);
        v4f him1 = *(const v4f*)(hp + 68);
        v4f ph0  = *(const v4f*)(rp);
        v4f ph1  = *(const v4f*)(rp + 4);
        v4f rr0, rr1, ri0, ri1;
#pragma unroll
        for (int j = 0; j < 4; ++j) {
            float rev0 = ph0[j] * INV_TWO_EMB;       // phase/(2pi) in [-0.5,0.5]
            float s0 = __builtin_amdgcn_sinf(rev0);  // v_sin_f32: revolutions
            float c0 = __builtin_amdgcn_cosf(rev0);
            rr0[j] = hre0[j] * c0 - him0[j] * s0;
            ri0[j] = hre0[j] * s0 + him0[j] * c0;
            float rev1 = ph1[j] * INV_TWO_EMB;
            float s1 = __builtin_amdgcn_sinf(rev1);
            float c1 = __builtin_amdgcn_cosf(rev1);
            rr1[j] = hre1[j] * c1 - him1[j] * s1;
            ri1[j] = hre1[j] * s1 + him1[j] * c1;
        }
        RR[0] = lo2(rr0); RR[1] = hi2(rr0); RR[2] = lo2(rr1); RR[3] = hi2(rr1);
        RI[0] = lo2(ri0); RI[1] = hi2(ri0); RI[2] = lo2(ri1); RI[3] = hi2(ri1);
    }

    float* obase = out + (size_t)b * NUM_E;
    const int elast = NUM_E - 1;        // prefetch clamp for the last block

#pragma unroll 1
    for (int q = 0; q < 4; ++q) {
        const int eb = e0 + q * 4;
        v4f vout;
        LOADE(B0, B1, B2, B3, eb + 1);                   // prefetch e+1
        vout[0] = dist_entity(A0, A1, A2, A3, RR, RI);
        LOADE(A0, A1, A2, A3, eb + 2);                   // prefetch e+2
        vout[1] = dist_entity(B0, B1, B2, B3, RR, RI);
        LOADE(B0, B1, B2, B3, eb + 3);                   // prefetch e+3
        vout[2] = dist_entity(A0, A1, A2, A3, RR, RI);
        {
            int en = eb + 4; en = (en > elast) ? elast : en;
            LOADE(A0, A1, A2, A3, en);                   // prefetch next quad
        }
        vout[3] = dist_entity(B0, B1, B2, B3, RR, RI);
        // quad q stored by the dg==q lanes: 8 batch rows x one 16B segment
        if (dg == q) *(v4f*)(obase + eb) = vout;
    }
}

extern "C" void kernel_launch(void* const* d_in, const int* in_sizes, int n_in,
                              void* d_out, int out_size, void* d_ws, size_t ws_size,
                              hipStream_t stream) {
    const int*   facts = (const int*)d_in[0];
    const float* ent   = (const float*)d_in[1];
    const float* rel   = (const float*)d_in[2];
    float*       out   = (float*)d_out;
    (void)d_ws; (void)ws_size;

    // 6250 blocks x 16 entities/block = 100000 exactly
    rotate_dist_fused<<<dim3(NUM_E / 16), dim3(256), 0, stream>>>(facts, ent, rel, out);
}

// Round 8
// 133.443 us; speedup vs baseline: 1.0291x; 1.0291x over previous
//
#include <hip/hip_runtime.h>
#include <math.h>

#define NUM_E   100000
#define GAMMA_F 12.0f
#define EMB_RANGE_F 0.21875f                       // (12+2)/64
#define INV_TWO_EMB (1.0f / (2.0f * EMB_RANGE_F))  // rev = r * this = phase/(2pi)

typedef float v4f __attribute__((ext_vector_type(4)));
typedef float v2f __attribute__((ext_vector_type(2)));

// ---- packed-f32 VALU (VOP3P): 2 dims per instruction ----
static __device__ __forceinline__ v2f pk_sub(v2f a, v2f b) {
    v2f d;
    asm("v_pk_add_f32 %0, %1, %2 neg_lo:[0,1] neg_hi:[0,1]"
        : "=v"(d) : "v"(a), "v"(b));
    return d;
}
static __device__ __forceinline__ v2f pk_mul(v2f a, v2f b) {
    v2f d;
    asm("v_pk_mul_f32 %0, %1, %2" : "=v"(d) : "v"(a), "v"(b));
    return d;
}
static __device__ __forceinline__ v2f pk_fma(v2f a, v2f b, v2f c) {
    v2f d;
    asm("v_pk_fma_f32 %0, %1, %2, %3" : "=v"(d) : "v"(a), "v"(b), "v"(c));
    return d;
}
static __device__ __forceinline__ float sq2(v2f dx, v2f dy) {
    v2f sq = pk_fma(dy, dy, pk_mul(dx, dx));
    return __builtin_amdgcn_sqrtf(sq.x) + __builtin_amdgcn_sqrtf(sq.y);
}
static __device__ __forceinline__ v2f lo2(v4f v) { return __builtin_shufflevector(v, v, 0, 1); }
static __device__ __forceinline__ v2f hi2(v4f v) { return __builtin_shufflevector(v, v, 2, 3); }

// cross-lane add via DPP (VALU pipe, no DS, no lgkm wait)
// 0xB1 = quad_perm [1,0,3,2] (xor1), 0x4E = quad_perm [2,3,0,1] (xor2),
// 0x141 = row_half_mirror: after xor1+xor2, mirrors within each aligned 8-lane
// half -> adds the other quad. Valid for any aligned 8-lane reduce group.
template <int CTRL>
static __device__ __forceinline__ float dpp_xor_add(float x) {
    int y = __builtin_amdgcn_update_dpp(0, __float_as_int(x), CTRL, 0xF, 0xF, true);
    return x + __int_as_float(y);
}

// distance for ONE entity vs this lane's 1 batch x 8 dims, reduced over the
// 8 dg lanes of the batch-group (all 8 lanes end with the result)
static __device__ __forceinline__ float dist_entity(
        v4f er0, v4f er1, v4f ei0, v4f ei1,
        const v2f RR[4], const v2f RI[4]) {
    v2f e2[4] = { lo2(er0), hi2(er0), lo2(er1), hi2(er1) };
    v2f i2[4] = { lo2(ei0), hi2(ei0), lo2(ei1), hi2(ei1) };
    float s0 = sq2(pk_sub(RR[0], e2[0]), pk_sub(RI[0], i2[0]));
    float s1 = sq2(pk_sub(RR[1], e2[1]), pk_sub(RI[1], i2[1]));
    float s2 = sq2(pk_sub(RR[2], e2[2]), pk_sub(RI[2], i2[2]));
    float s3 = sq2(pk_sub(RR[3], e2[3]), pk_sub(RI[3], i2[3]));
    float v = (s0 + s1) + (s2 + s3);
    v = dpp_xor_add<0xB1>(v);            // xor1 (within quad)
    v = dpp_xor_add<0x4E>(v);            // xor2 (within quad)
    v = dpp_xor_add<0x141>(v);           // xor4 via row_half_mirror
    return GAMMA_F - v;
}

#define LOADE(d0, d1, d2, d3, EIDX) do {                         \
    const float* _p = ent + (size_t)(EIDX) * 128 + dg * 8;       \
    d0 = *(const v4f*)(_p);      d1 = *(const v4f*)(_p + 4);     \
    d2 = *(const v4f*)(_p + 64); d3 = *(const v4f*)(_p + 68); } while (0)

// R14 = R13 decomposition + ENFORCED 4-deep register prefetch.
// R13 diagnosis: VGPR_Count=40 < the ~60 the written pipeline needs -> the
// scheduler SANK the A/B prefetch loads to their consumers (zero effective
// depth), leaving ~122cy of compute against 400-900cy L3/HBM latency = the
// 73us regression. R10's 48us was the same disease at 1-deep (VGPR 60: B
// buffer sunk too); per-SIMD issue occupancy was only ~20-25%.
// Fix: 4 named entity buffers (P0-P3, 64 VGPRs); each buffer's load issues 4
// entities (~500cy of own-wave issue + cross-wave overlap) before its use.
// __builtin_amdgcn_sched_barrier(0) after every prefetch issue pins the
// schedule: loads cannot sink, compute cannot hoist. Global loads cannot be
// rematerialized, and the (256,2)=128-reg cap leaves room (live ~100) so the
// allocator can neither remat nor spill the pipeline away.
// Trade accepted: 4 waves/SIMD (was 8) -- ILP in place of TLP, enforced.
__global__ __launch_bounds__(256, 2) void rotate_dist_fused(
        const int*   __restrict__ facts,
        const float* __restrict__ ent,
        const float* __restrict__ rel,
        float*       __restrict__ out) {
    const int t    = threadIdx.x;
    const int lane = t & 63;
    const int wv   = t >> 6;
    const int bq   = lane >> 3;         // batch-in-wave 0..7
    const int dg   = lane & 7;          // dims 8dg..8dg+7
    const int b    = wv * 8 + bq;       // global batch 0..31
    const int e0   = blockIdx.x * 16;   // this block's 16 entities

    // ---- prologue loads first (facts/head/rel), then the 4 prefetches ----
    const int f0 = facts[b * 3 + 0];
    const int f1 = facts[b * 3 + 1];
    const float* hp = ent + (size_t)f0 * 128 + dg * 8;
    const float* rp = rel + (size_t)f1 * 64  + dg * 8;
    v4f hre0 = *(const v4f*)(hp);
    v4f hre1 = *(const v4f*)(hp + 4);
    v4f him0 = *(const v4f*)(hp + 64);
    v4f him1 = *(const v4f*)(hp + 68);
    v4f ph0  = *(const v4f*)(rp);
    v4f ph1  = *(const v4f*)(rp + 4);

    v4f P0a, P0b, P0c, P0d, P1a, P1b, P1c, P1d;
    v4f P2a, P2b, P2c, P2d, P3a, P3b, P3c, P3d;
    LOADE(P0a, P0b, P0c, P0d, e0 + 0);
    LOADE(P1a, P1b, P1c, P1d, e0 + 1);
    LOADE(P2a, P2b, P2c, P2d, e0 + 2);
    LOADE(P3a, P3b, P3c, P3d, e0 + 3);
    __builtin_amdgcn_sched_barrier(0);   // prefetches stay issued HERE

    // ---- rot slice (1 batch x 8 dims) in registers; hides prefetch latency ----
    v2f RR[4], RI[4];
    {
        v4f rr0, rr1, ri0, ri1;
#pragma unroll
        for (int j = 0; j < 4; ++j) {
            float rev0 = ph0[j] * INV_TWO_EMB;       // phase/(2pi) in [-0.5,0.5]
            float s0 = __builtin_amdgcn_sinf(rev0);  // v_sin_f32: revolutions
            float c0 = __builtin_amdgcn_cosf(rev0);
            rr0[j] = hre0[j] * c0 - him0[j] * s0;
            ri0[j] = hre0[j] * s0 + him0[j] * c0;
            float rev1 = ph1[j] * INV_TWO_EMB;
            float s1 = __builtin_amdgcn_sinf(rev1);
            float c1 = __builtin_amdgcn_cosf(rev1);
            rr1[j] = hre1[j] * c1 - him1[j] * s1;
            ri1[j] = hre1[j] * s1 + him1[j] * c1;
        }
        RR[0] = lo2(rr0); RR[1] = hi2(rr0); RR[2] = lo2(rr1); RR[3] = hi2(rr1);
        RI[0] = lo2(ri0); RI[1] = hi2(ri0); RI[2] = lo2(ri1); RI[3] = hi2(ri1);
    }

    float* obase = out + (size_t)b * NUM_E;
    const int elast = NUM_E - 1;        // prefetch clamp for the last block

    // slot S: consume buffer S (entity eb+S), refill it for entity eb+4+S,
    // pin the schedule so the refill cannot sink toward its use next round.
#define SLOT(Pa, Pb, Pc, Pd, S) do {                               \
        vout[S] = dist_entity(Pa, Pb, Pc, Pd, RR, RI);             \
        int _en = eb + 4 + (S);                                    \
        _en = (_en > elast) ? elast : _en;                         \
        LOADE(Pa, Pb, Pc, Pd, _en);                                \
        __builtin_amdgcn_sched_barrier(0);                         \
    } while (0)

#pragma unroll
    for (int q = 0; q < 4; ++q) {
        const int eb = e0 + q * 4;
        v4f vout;
        SLOT(P0a, P0b, P0c, P0d, 0);
        SLOT(P1a, P1b, P1c, P1d, 1);
        SLOT(P2a, P2b, P2c, P2d, 2);
        SLOT(P3a, P3b, P3c, P3d, 3);
        // quad q stored by the dg==q lanes: 8 batch rows x one 16B segment
        if (dg == q) *(v4f*)(obase + eb) = vout;
    }
#undef SLOT
}

extern "C" void kernel_launch(void* const* d_in, const int* in_sizes, int n_in,
                              void* d_out, int out_size, void* d_ws, size_t ws_size,
                              hipStream_t stream) {
    const int*   facts = (const int*)d_in[0];
    const float* ent   = (const float*)d_in[1];
    const float* rel   = (const float*)d_in[2];
    float*       out   = (float*)d_out;
    (void)d_ws; (void)ws_size;

    // 6250 blocks x 16 entities/block = 100000 exactly
    rotate_dist_fused<<<dim3(NUM_E / 16), dim3(256), 0, stream>>>(facts, ent, rel, out);
}

// Round 9
// 116.473 us; speedup vs baseline: 1.1790x; 1.1457x over previous
//
#include <hip/hip_runtime.h>
#include <math.h>

#define NUM_E   100000
#define GAMMA_F 12.0f
#define EMB_RANGE_F 0.21875f                       // (12+2)/64
#define INV_TWO_EMB (1.0f / (2.0f * EMB_RANGE_F))  // rev = r * this = phase/(2pi)

#define TILE_E  16                                 // entities per LDS tile (8 KB)
#define NT      (NUM_E / TILE_E)                   // 6250 tiles exactly
#define GRID    2048                               // 8 blocks/CU exactly

typedef float v4f __attribute__((ext_vector_type(4)));
typedef float v2f __attribute__((ext_vector_type(2)));

// ---- packed-f32 VALU (VOP3P): 2 dims per instruction ----
static __device__ __forceinline__ v2f pk_sub(v2f a, v2f b) {
    v2f d;
    asm("v_pk_add_f32 %0, %1, %2 neg_lo:[0,1] neg_hi:[0,1]"
        : "=v"(d) : "v"(a), "v"(b));
    return d;
}
static __device__ __forceinline__ v2f pk_mul(v2f a, v2f b) {
    v2f d;
    asm("v_pk_mul_f32 %0, %1, %2" : "=v"(d) : "v"(a), "v"(b));
    return d;
}
static __device__ __forceinline__ v2f pk_fma(v2f a, v2f b, v2f c) {
    v2f d;
    asm("v_pk_fma_f32 %0, %1, %2, %3" : "=v"(d) : "v"(a), "v"(b), "v"(c));
    return d;
}
static __device__ __forceinline__ float sq2(v2f dx, v2f dy) {
    v2f sq = pk_fma(dy, dy, pk_mul(dx, dx));
    return __builtin_amdgcn_sqrtf(sq.x) + __builtin_amdgcn_sqrtf(sq.y);
}
static __device__ __forceinline__ v2f lo2(v4f v) { return __builtin_shufflevector(v, v, 0, 1); }
static __device__ __forceinline__ v2f hi2(v4f v) { return __builtin_shufflevector(v, v, 2, 3); }

// cross-lane add via DPP (VALU pipe, no DS, no lgkm wait)
// 0xB1 = quad_perm [1,0,3,2] (xor1), 0x4E = quad_perm [2,3,0,1] (xor2),
// 0x141 = row_half_mirror: after xor1+xor2 it adds the other quad of the
// aligned 8-lane group. Verified passing R8-R14.
template <int CTRL>
static __device__ __forceinline__ float dpp_xor_add(float x) {
    int y = __builtin_amdgcn_update_dpp(0, __float_as_int(x), CTRL, 0xF, 0xF, true);
    return x + __int_as_float(y);
}

// distance for ONE entity vs this lane's 1 batch x 8 dims, reduced over the
// 8 dg lanes of the batch-group (all 8 lanes end with the result)
static __device__ __forceinline__ float dist_entity(
        v4f er0, v4f er1, v4f ei0, v4f ei1,
        const v2f RR[4], const v2f RI[4]) {
    v2f e2[4] = { lo2(er0), hi2(er0), lo2(er1), hi2(er1) };
    v2f i2[4] = { lo2(ei0), hi2(ei0), lo2(ei1), hi2(ei1) };
    float s0 = sq2(pk_sub(RR[0], e2[0]), pk_sub(RI[0], i2[0]));
    float s1 = sq2(pk_sub(RR[1], e2[1]), pk_sub(RI[1], i2[1]));
    float s2 = sq2(pk_sub(RR[2], e2[2]), pk_sub(RI[2], i2[2]));
    float s3 = sq2(pk_sub(RR[3], e2[3]), pk_sub(RI[3], i2[3]));
    float v = (s0 + s1) + (s2 + s3);
    v = dpp_xor_add<0xB1>(v);            // xor1 (within quad)
    v = dpp_xor_add<0x4E>(v);            // xor2 (within quad)
    v = dpp_xor_add<0x141>(v);           // xor4 via row_half_mirror
    return GAMMA_F - v;
}

// async global->LDS DMA, width 16: 64 lanes x 16B = 1 KB per instruction.
// g is the PER-LANE source (base + lane*16B); l is the WAVE-UNIFORM LDS base
// (HW adds lane*16B). No destination register exists -> the register
// allocator cannot sink/compress this pipeline (the R11-R14 failure mode).
static __device__ __forceinline__ void stage_chunk(const float* g, float* l) {
    __builtin_amdgcn_global_load_lds(
        (const __attribute__((address_space(1))) void*)g,
        (__attribute__((address_space(3))) void*)l,
        16, 0, 0);
}

// R15: R13 decomposition (rot register-resident, 16 f32/lane; no allocator
// fight) + entity stream staged through double-buffered LDS via
// global_load_lds. Pipeline depth lives in LDS, not registers -- the compiler
// provably preserves it (m97 pattern). One barrier per tile; its vmcnt drain
// lands ~2500cy after the DMA issue, i.e. free.
//  - Block = 4 waves; wave wv owns batches wv*8..wv*8+7; lane=(bq,dg).
//  - Tile = 16 entities = 8 KB contiguous span of ent; 2 chunks/wave staged.
//  - Compute reads ds_read_b128 x4/entity (8-lane broadcast, conflict-free).
//  - Grid-stride over 6250 tiles with GRID=2048 (8 blocks/CU exactly).
__global__ __launch_bounds__(256, 2) void rotate_dist_fused(
        const int*   __restrict__ facts,
        const float* __restrict__ ent,
        const float* __restrict__ rel,
        float*       __restrict__ out) {
    __shared__ __align__(16) float sbuf[2][TILE_E * 128];   // 2 x 8 KB

    const int t    = threadIdx.x;
    const int lane = t & 63;
    const int wv   = t >> 6;
    const int bq   = lane >> 3;         // batch-in-wave 0..7
    const int dg   = lane & 7;          // dims 8dg..8dg+7
    const int b    = wv * 8 + bq;       // global batch 0..31

    int tile = blockIdx.x;

    // ---- stage first tile into buf0 (latency hides under the prologue) ----
    {
        const float* g = ent + (size_t)tile * (TILE_E * 128) + wv * 512 + lane * 4;
        float* l = &sbuf[0][wv * 512];
        stage_chunk(g, l);
        stage_chunk(g + 256, l + 256);
    }

    // ---- rot slice (1 batch x 8 dims) in registers ----
    v2f RR[4], RI[4];
    {
        const int f0 = facts[b * 3 + 0];
        const int f1 = facts[b * 3 + 1];
        const float* hp = ent + (size_t)f0 * 128 + dg * 8;
        const float* rp = rel + (size_t)f1 * 64  + dg * 8;
        v4f hre0 = *(const v4f*)(hp);
        v4f hre1 = *(const v4f*)(hp + 4);
        v4f him0 = *(const v4f*)(hp + 64);
        v4f him1 = *(const v4f*)(hp + 68);
        v4f ph0  = *(const v4f*)(rp);
        v4f ph1  = *(const v4f*)(rp + 4);
        v4f rr0, rr1, ri0, ri1;
#pragma unroll
        for (int j = 0; j < 4; ++j) {
            float rev0 = ph0[j] * INV_TWO_EMB;       // phase/(2pi) in [-0.5,0.5]
            float s0 = __builtin_amdgcn_sinf(rev0);  // v_sin_f32: revolutions
            float c0 = __builtin_amdgcn_cosf(rev0);
            rr0[j] = hre0[j] * c0 - him0[j] * s0;
            ri0[j] = hre0[j] * s0 + him0[j] * c0;
            float rev1 = ph1[j] * INV_TWO_EMB;
            float s1 = __builtin_amdgcn_sinf(rev1);
            float c1 = __builtin_amdgcn_cosf(rev1);
            rr1[j] = hre1[j] * c1 - him1[j] * s1;
            ri1[j] = hre1[j] * s1 + him1[j] * c1;
        }
        RR[0] = lo2(rr0); RR[1] = hi2(rr0); RR[2] = lo2(rr1); RR[3] = hi2(rr1);
        RI[0] = lo2(ri0); RI[1] = hi2(ri0); RI[2] = lo2(ri1); RI[3] = hi2(ri1);
    }

    float* obase = out + (size_t)b * NUM_E;

    int cur = 0;
    __syncthreads();        // buf0 landed (barrier drains vmcnt)

    while (true) {
        const int nxt = tile + GRID;
        if (nxt < NT) {     // issue next-tile DMA before computing current
            const float* g = ent + (size_t)nxt * (TILE_E * 128) + wv * 512 + lane * 4;
            float* l = &sbuf[cur ^ 1][wv * 512];
            stage_chunk(g, l);
            stage_chunk(g + 256, l + 256);
        }

        // ---- compute current tile from LDS ----
        const float* csrc = &sbuf[cur][0];
        float* op = obase + tile * TILE_E;
#pragma unroll
        for (int q = 0; q < 4; ++q) {
            v4f vout;
#pragma unroll
            for (int i = 0; i < 4; ++i) {
                const float* ep = csrc + (q * 4 + i) * 128 + dg * 8;
                v4f er0 = *(const v4f*)(ep);         // ds_read_b128, broadcast x8
                v4f er1 = *(const v4f*)(ep + 4);
                v4f ei0 = *(const v4f*)(ep + 64);
                v4f ei1 = *(const v4f*)(ep + 68);
                vout[i] = dist_entity(er0, er1, ei0, ei1, RR, RI);
            }
            // quad q stored by the dg==q lanes: 8 batch rows x one 16B segment
            if (dg == q) *(v4f*)(op + q * 4) = vout;
        }

        if (nxt >= NT) break;
        __syncthreads();    // next buf landed; everyone done reading cur
        cur ^= 1;
        tile = nxt;
    }
}

extern "C" void kernel_launch(void* const* d_in, const int* in_sizes, int n_in,
                              void* d_out, int out_size, void* d_ws, size_t ws_size,
                              hipStream_t stream) {
    const int*   facts = (const int*)d_in[0];
    const float* ent   = (const float*)d_in[1];
    const float* rel   = (const float*)d_in[2];
    float*       out   = (float*)d_out;
    (void)d_ws; (void)ws_size;

    rotate_dist_fused<<<dim3(GRID), dim3(256), 0, stream>>>(facts, ent, rel, out);
}

// Round 10
// 114.870 us; speedup vs baseline: 1.1955x; 1.0140x over previous
//
#include <hip/hip_runtime.h>
#include <math.h>

#define NUM_E   100000
#define GAMMA_F 12.0f
#define EMB_RANGE_F 0.21875f                       // (12+2)/64
#define INV_TWO_EMB (1.0f / (2.0f * EMB_RANGE_F))  // rev = r * this = phase/(2pi)

#define TILE_E  16                                 // entities per LDS tile (8 KB)
#define NT      (NUM_E / TILE_E)                   // 6250 tiles exactly
#define GRID    2048                               // 8 blocks/CU exactly

typedef float v4f __attribute__((ext_vector_type(4)));
typedef float v2f __attribute__((ext_vector_type(2)));

// ---- packed-f32 VALU (VOP3P): 2 dims per instruction ----
static __device__ __forceinline__ v2f pk_sub(v2f a, v2f b) {
    v2f d;
    asm("v_pk_add_f32 %0, %1, %2 neg_lo:[0,1] neg_hi:[0,1]"
        : "=v"(d) : "v"(a), "v"(b));
    return d;
}
static __device__ __forceinline__ v2f pk_mul(v2f a, v2f b) {
    v2f d;
    asm("v_pk_mul_f32 %0, %1, %2" : "=v"(d) : "v"(a), "v"(b));
    return d;
}
static __device__ __forceinline__ v2f pk_fma(v2f a, v2f b, v2f c) {
    v2f d;
    asm("v_pk_fma_f32 %0, %1, %2, %3" : "=v"(d) : "v"(a), "v"(b), "v"(c));
    return d;
}
static __device__ __forceinline__ float sq2(v2f dx, v2f dy) {
    v2f sq = pk_fma(dy, dy, pk_mul(dx, dx));
    return __builtin_amdgcn_sqrtf(sq.x) + __builtin_amdgcn_sqrtf(sq.y);
}
static __device__ __forceinline__ v2f lo2(v4f v) { return __builtin_shufflevector(v, v, 0, 1); }
static __device__ __forceinline__ v2f hi2(v4f v) { return __builtin_shufflevector(v, v, 2, 3); }

// cross-lane add via DPP (VALU pipe, no DS, no lgkm wait)
// 0xB1 = quad_perm [1,0,3,2] (xor1), 0x4E = quad_perm [2,3,0,1] (xor2),
// 0x141 = row_half_mirror: after xor1+xor2 it adds the other quad of the
// aligned 8-lane group. Verified passing R8-R15.
template <int CTRL>
static __device__ __forceinline__ float dpp_xor_add(float x) {
    int y = __builtin_amdgcn_update_dpp(0, __float_as_int(x), CTRL, 0xF, 0xF, true);
    return x + __int_as_float(y);
}

// distance for ONE entity vs this lane's 1 batch x 8 dims, reduced over the
// 8 dg lanes of the batch-group (all 8 lanes end with the result)
static __device__ __forceinline__ float dist_entity(
        v4f er0, v4f er1, v4f ei0, v4f ei1,
        const v2f RR[4], const v2f RI[4]) {
    v2f e2[4] = { lo2(er0), hi2(er0), lo2(er1), hi2(er1) };
    v2f i2[4] = { lo2(ei0), hi2(ei0), lo2(ei1), hi2(ei1) };
    float s0 = sq2(pk_sub(RR[0], e2[0]), pk_sub(RI[0], i2[0]));
    float s1 = sq2(pk_sub(RR[1], e2[1]), pk_sub(RI[1], i2[1]));
    float s2 = sq2(pk_sub(RR[2], e2[2]), pk_sub(RI[2], i2[2]));
    float s3 = sq2(pk_sub(RR[3], e2[3]), pk_sub(RI[3], i2[3]));
    float v = (s0 + s1) + (s2 + s3);
    v = dpp_xor_add<0xB1>(v);            // xor1 (within quad)
    v = dpp_xor_add<0x4E>(v);            // xor2 (within quad)
    v = dpp_xor_add<0x141>(v);           // xor4 via row_half_mirror
    return GAMMA_F - v;
}

// async global->LDS DMA, width 16: 64 lanes x 16B = 1 KB per instruction.
// g is the PER-LANE source (base + lane*16B); l is the WAVE-UNIFORM LDS base
// (HW adds lane*16B). No destination register exists -> the register
// allocator cannot sink/compress this pipeline (the R11-R14 failure mode).
static __device__ __forceinline__ void stage_chunk(const float* g, float* l) {
    __builtin_amdgcn_global_load_lds(
        (const __attribute__((address_space(1))) void*)g,
        (__attribute__((address_space(3))) void*)l,
        16, 0, 0);
}

// R16 = R15 + in-tile 1-entity LDS-read lookahead.
// R15 diagnosis: WRITE exactly ideal (no spill), VALUBusy 61%, VGPR=32 --
// at a 32-reg allocation the compiler cannot hold two entities' LDS data,
// so it serialized read->lgkmwait(~120cy)->compute per entity; the unhidden
// remainder is the 39% idle issue. DS instr count is invariant (16
// b128/entity for any 256-thread decomposition), so the lever is intra-wave
// overlap, not fewer reads.
// Fix: double register set (cur/nxt, 32 VGPR); issue entity i+1's 4
// ds_read_b128 BEFORE computing entity i, pinned with sched_barrier(0) so
// the scheduler cannot sink them back (R11/R13 disease). Live set ~60 VGPR
// sits inside the allocator's preferred <=64 envelope -> no incentive to
// undo it. Each entity's ~134cy compute covers the next's ~120cy LDS latency.
__global__ __launch_bounds__(256, 2) void rotate_dist_fused(
        const int*   __restrict__ facts,
        const float* __restrict__ ent,
        const float* __restrict__ rel,
        float*       __restrict__ out) {
    __shared__ __align__(16) float sbuf[2][TILE_E * 128];   // 2 x 8 KB

    const int t    = threadIdx.x;
    const int lane = t & 63;
    const int wv   = t >> 6;
    const int bq   = lane >> 3;         // batch-in-wave 0..7
    const int dg   = lane & 7;          // dims 8dg..8dg+7
    const int b    = wv * 8 + bq;       // global batch 0..31

    int tile = blockIdx.x;

    // ---- stage first tile into buf0 (latency hides under the prologue) ----
    {
        const float* g = ent + (size_t)tile * (TILE_E * 128) + wv * 512 + lane * 4;
        float* l = &sbuf[0][wv * 512];
        stage_chunk(g, l);
        stage_chunk(g + 256, l + 256);
    }

    // ---- rot slice (1 batch x 8 dims) in registers ----
    v2f RR[4], RI[4];
    {
        const int f0 = facts[b * 3 + 0];
        const int f1 = facts[b * 3 + 1];
        const float* hp = ent + (size_t)f0 * 128 + dg * 8;
        const float* rp = rel + (size_t)f1 * 64  + dg * 8;
        v4f hre0 = *(const v4f*)(hp);
        v4f hre1 = *(const v4f*)(hp + 4);
        v4f him0 = *(const v4f*)(hp + 64);
        v4f him1 = *(const v4f*)(hp + 68);
        v4f ph0  = *(const v4f*)(rp);
        v4f ph1  = *(const v4f*)(rp + 4);
        v4f rr0, rr1, ri0, ri1;
#pragma unroll
        for (int j = 0; j < 4; ++j) {
            float rev0 = ph0[j] * INV_TWO_EMB;       // phase/(2pi) in [-0.5,0.5]
            float s0 = __builtin_amdgcn_sinf(rev0);  // v_sin_f32: revolutions
            float c0 = __builtin_amdgcn_cosf(rev0);
            rr0[j] = hre0[j] * c0 - him0[j] * s0;
            ri0[j] = hre0[j] * s0 + him0[j] * c0;
            float rev1 = ph1[j] * INV_TWO_EMB;
            float s1 = __builtin_amdgcn_sinf(rev1);
            float c1 = __builtin_amdgcn_cosf(rev1);
            rr1[j] = hre1[j] * c1 - him1[j] * s1;
            ri1[j] = hre1[j] * s1 + him1[j] * c1;
        }
        RR[0] = lo2(rr0); RR[1] = hi2(rr0); RR[2] = lo2(rr1); RR[3] = hi2(rr1);
        RI[0] = lo2(ri0); RI[1] = hi2(ri0); RI[2] = lo2(ri1); RI[3] = hi2(ri1);
    }

    float* obase = out + (size_t)b * NUM_E;

    int cur = 0;
    __syncthreads();        // buf0 landed (barrier drains vmcnt)

    while (true) {
        const int nxt = tile + GRID;
        if (nxt < NT) {     // issue next-tile DMA before computing current
            const float* g = ent + (size_t)nxt * (TILE_E * 128) + wv * 512 + lane * 4;
            float* l = &sbuf[cur ^ 1][wv * 512];
            stage_chunk(g, l);
            stage_chunk(g + 256, l + 256);
        }

        // ---- compute current tile from LDS, 1-entity read lookahead ----
        const float* csrc = &sbuf[cur][0] + dg * 8;
        float* op = obase + tile * TILE_E;

        v4f C0, C1, C2, C3, N0, N1, N2, N3;
        C0 = *(const v4f*)(csrc);            // entity 0 of this tile
        C1 = *(const v4f*)(csrc + 4);
        C2 = *(const v4f*)(csrc + 64);
        C3 = *(const v4f*)(csrc + 68);
        __builtin_amdgcn_sched_barrier(0);

#pragma unroll
        for (int q = 0; q < 4; ++q) {
            v4f vout;
#pragma unroll
            for (int i = 0; i < 4; ++i) {
                const int nidx = q * 4 + i + 1;
                const float* np = csrc + (nidx < 16 ? nidx : 15) * 128;
                N0 = *(const v4f*)(np);      // issue next-entity reads...
                N1 = *(const v4f*)(np + 4);
                N2 = *(const v4f*)(np + 64);
                N3 = *(const v4f*)(np + 68);
                __builtin_amdgcn_sched_barrier(0);   // ...pinned above compute
                vout[i] = dist_entity(C0, C1, C2, C3, RR, RI);
                C0 = N0; C1 = N1; C2 = N2; C3 = N3;
            }
            // quad q stored by the dg==q lanes: 8 batch rows x one 16B segment
            if (dg == q) *(v4f*)(op + q * 4) = vout;
        }

        if (nxt >= NT) break;
        __syncthreads();    // next buf landed; everyone done reading cur
        cur ^= 1;
        tile = nxt;
    }
}

extern "C" void kernel_launch(void* const* d_in, const int* in_sizes, int n_in,
                              void* d_out, int out_size, void* d_ws, size_t ws_size,
                              hipStream_t stream) {
    const int*   facts = (const int*)d_in[0];
    const float* ent   = (const float*)d_in[1];
    const float* rel   = (const float*)d_in[2];
    float*       out   = (float*)d_out;
    (void)d_ws; (void)ws_size;

    rotate_dist_fused<<<dim3(GRID), dim3(256), 0, stream>>>(facts, ent, rel, out);
}